// Round 3
// baseline (517.628 us; speedup 1.0000x reference)
//
#include <hip/hip_runtime.h>

#define Nn 8192
#define Bb 4
#define KK 20
#define OO 64
#define EPSF 1e-5f
#define SLOPEF 0.2f
#define FDEPTH 12

// ---------------- pack: P[b][j] = (x,y,z, |x|^2) ------------------------------------------

__global__ __launch_bounds__(256) void pack_kernel(const float* __restrict__ x,
                                                   float4* __restrict__ P) {
  int gid = blockIdx.x * 256 + threadIdx.x;      // b*N + j
  int b = gid >> 13, j = gid & (Nn - 1);
  const float* xb = x + b * 3 * Nn;
  float a0 = xb[j], a1 = xb[Nn + j], a2 = xb[2 * Nn + j];
  P[gid] = make_float4(a0, a1, a2, a0 * a0 + a1 * a1 + a2 * a2);
}

// ---------------- KNN: exact top-20 (incl. self), ties -> lower index ----------------------

__device__ __forceinline__ void qinsert(float cd, int ci, float bd[KK], int bi[KK]) {
  // ascending-sorted insert; strict < keeps earlier-index on ties (candidates arrive in
  // ascending m order within a wave)
  #pragma unroll
  for (int j = 0; j < KK; ++j) {
    bool sw = cd < bd[j];
    float td = bd[j]; int ti = bi[j];
    bd[j] = sw ? cd : td;
    bi[j] = sw ? ci : ti;
    cd = sw ? td : cd;
    ci = sw ? ti : ci;
  }
}

// tie-aware variant for the tree merge (incoming indices not ordered vs incumbent)
__device__ __forceinline__ void qinsert_tie(float cd, int ci, float bd[KK], int bi[KK]) {
  #pragma unroll
  for (int j = 0; j < KK; ++j) {
    bool sw = (cd < bd[j]) || (cd == bd[j] && ci < bi[j]);
    float td = bd[j]; int ti = bi[j];
    bd[j] = sw ? cd : td;
    bi[j] = sw ? ci : ti;
    cd = sw ? td : cd;
    ci = sw ? ti : ci;
  }
}

#define APPEND(dv, iv)                                                        \
  do {                                                                        \
    _Pragma("unroll")                                                         \
    for (int s = 0; s < FDEPTH; ++s) if (fcnt == s) { fb[s] = (dv); fi[s] = (iv); } \
    fcnt++;                                                                   \
  } while (0)

__global__ __launch_bounds__(512, 4) void knn_kernel(const float4* __restrict__ P,
                                                     int* __restrict__ idx_out) {
  // 512 threads = 8 waves; wave w scans segment [w*1024, w*1024+1024) for the same
  // 64 rows (lane = row). Shared per-row threshold in LDS collapses accept counts.
  __shared__ float    lmd[4][64][KK + 1];
  __shared__ int      lmi[4][64][KK + 1];
  __shared__ unsigned lds_thr[64];

  const int b    = blockIdx.y;
  const int lane = threadIdx.x & 63;
  const int wid  = __builtin_amdgcn_readfirstlane(threadIdx.x >> 6);
  const int n    = blockIdx.x * 64 + lane;

  if (threadIdx.x < 64) lds_thr[threadIdx.x] = 0x7F800000u;   // +inf bits

  const float4* __restrict__ Pb = P + b * Nn;
  const float4 me = Pb[n];
  const float4* __restrict__ seg = Pb + wid * 1024;
  const int mbase = wid * 1024;

  float bd[KK]; int bi[KK];
  #pragma unroll
  for (int k = 0; k < KK; ++k) { bd[k] = __builtin_inff(); bi[k] = -1; }
  float fb[FDEPTH]; int fi[FDEPTH]; int fcnt = 0;
  #pragma unroll
  for (int s = 0; s < FDEPTH; ++s) { fb[s] = 0.f; fi[s] = 0; }
  float thr = __builtin_inff();

  __syncthreads();

  for (int c = 0; c < 8; ++c) {
    thr = fminf(thr, __uint_as_float(lds_thr[lane]));   // periodic refresh from other waves
    const int base = c * 128;
    for (int j = 0; j < 128; j += 4) {
      float4 p0 = seg[base + j + 0];
      float4 p1 = seg[base + j + 1];
      float4 p2 = seg[base + j + 2];
      float4 p3 = seg[base + j + 3];
      float d0 = fmaf(-2.f, me.x * p0.x + me.y * p0.y + me.z * p0.z, me.w + p0.w);
      float d1 = fmaf(-2.f, me.x * p1.x + me.y * p1.y + me.z * p1.z, me.w + p1.w);
      float d2 = fmaf(-2.f, me.x * p2.x + me.y * p2.y + me.z * p2.z, me.w + p2.w);
      float d3 = fmaf(-2.f, me.x * p3.x + me.y * p3.y + me.z * p3.z, me.w + p3.w);
      bool a0 = d0 <= thr, a1 = d1 <= thr, a2 = d2 <= thr, a3 = d3 <= thr;
      if (__any(a0 || a1 || a2 || a3)) {
        if (__any(fcnt >= FDEPTH - 3)) {        // flush BEFORE appends: post max = 8+4 = 12
          #pragma unroll
          for (int s = 0; s < FDEPTH; ++s) if (s < fcnt) qinsert(fb[s], fi[s], bd, bi);
          fcnt = 0;
          unsigned old = atomicMin(&lds_thr[lane], __float_as_uint(bd[KK - 1]));
          thr = fminf(bd[KK - 1], __uint_as_float(old));
        }
        if (a0) APPEND(d0, mbase + base + j + 0);
        if (a1) APPEND(d1, mbase + base + j + 1);
        if (a2) APPEND(d2, mbase + base + j + 2);
        if (a3) APPEND(d3, mbase + base + j + 3);
      }
    }
  }
  // final flush
  #pragma unroll
  for (int s = 0; s < FDEPTH; ++s) if (s < fcnt) qinsert(fb[s], fi[s], bd, bi);

  // ---- log-tree merge: 8 -> 4 -> 2 -> 1 ----
  for (int stride = 4; stride >= 1; stride >>= 1) {
    __syncthreads();
    if (wid >= stride && wid < 2 * stride) {
      #pragma unroll
      for (int k = 0; k < KK; ++k) { lmd[wid - stride][lane][k] = bd[k]; lmi[wid - stride][lane][k] = bi[k]; }
    }
    __syncthreads();
    if (wid < stride) {
      #pragma unroll
      for (int k = 0; k < KK; ++k) {
        float cd = lmd[wid][lane][k]; int ci = lmi[wid][lane][k];
        if (!__ballot(cd < bd[KK - 1] || (cd == bd[KK - 1] && ci < bi[KK - 1]))) break;
        qinsert_tie(cd, ci, bd, bi);
      }
    }
  }
  if (wid == 0) {
    int* op = idx_out + (b * Nn + n) * KK;
    #pragma unroll
    for (int k = 0; k < KK; ++k) op[k] = bi[k];
  }
}

// ---------------- u = (Wa-Wb)·x_n, v = Wb·x_n  (layout [b][n][o], o contiguous) -------------

__global__ __launch_bounds__(256) void uv_kernel(const float* __restrict__ x,
                                                 const float* __restrict__ W,
                                                 float* __restrict__ u,
                                                 float* __restrict__ v) {
  int gid = blockIdx.x * 256 + threadIdx.x;
  int o  = gid & 63;
  int bn = gid >> 6;
  int b  = bn >> 13;
  int n  = bn & (Nn - 1);
  const float* xb = x + b * 3 * Nn;
  float x0 = xb[n], x1 = xb[Nn + n], x2 = xb[2 * Nn + n];
  float wa0 = W[o * 6 + 0], wa1 = W[o * 6 + 1], wa2 = W[o * 6 + 2];
  float wb0 = W[o * 6 + 3], wb1 = W[o * 6 + 4], wb2 = W[o * 6 + 5];
  u[gid] = (wa0 - wb0) * x0 + (wa1 - wb1) * x1 + (wa2 - wb2) * x2;
  v[gid] = wb0 * x0 + wb1 * x1 + wb2 * x2;
}

// ---------------- gather v over neighbors: pm = u + max_k v ; accumulate S1,S2 --------------

__global__ __launch_bounds__(256) void gather_kernel(const int* __restrict__ idx,
                                                     float* __restrict__ u,      // in-place -> pm
                                                     const float* __restrict__ v,
                                                     float* __restrict__ stats) {
  __shared__ float ls1[4][64], ls2[4][64];
  int b  = blockIdx.y;
  int o  = threadIdx.x & 63;
  int ys = threadIdx.x >> 6;
  const float* vb = v + (size_t)b * Nn * OO;
  float s1 = 0.f, s2 = 0.f;
  for (int i = 0; i < 16; ++i) {
    int n = blockIdx.x * 64 + ys * 16 + i;
    const int* ip = idx + (b * Nn + n) * KK;
    float un = u[(size_t)(b * Nn + n) * OO + o];
    float sv = 0.f, sv2 = 0.f, mv = -__builtin_inff();
    #pragma unroll
    for (int k = 0; k < KK; ++k) {
      int j = ip[k];
      float val = vb[(size_t)j * OO + o];
      sv += val; sv2 += val * val; mv = fmaxf(mv, val);
    }
    u[(size_t)(b * Nn + n) * OO + o] = un + mv;
    s1 += (float)KK * un + sv;
    s2 += (float)KK * un * un + 2.f * un * sv + sv2;
  }
  ls1[ys][o] = s1; ls2[ys][o] = s2;
  __syncthreads();
  if (ys == 0) {
    float t1 = ls1[0][o] + ls1[1][o] + ls1[2][o] + ls1[3][o];
    float t2 = ls2[0][o] + ls2[1][o] + ls2[2][o] + ls2[3][o];
    atomicAdd(&stats[(b * OO + o) * 2 + 0], t1);
    atomicAdd(&stats[(b * OO + o) * 2 + 1], t2);
  }
}

// ---------------- finalize: normalize + lrelu + transpose to [b][o][n] ----------------------

__global__ __launch_bounds__(256) void out_kernel(const float* __restrict__ pm,
                                                  const float* __restrict__ stats,
                                                  float* __restrict__ out) {
  __shared__ float tile[64][65];
  int b  = blockIdx.y;
  int o  = threadIdx.x & 63;
  int ys = threadIdx.x >> 6;
  const float inv_cnt = 1.0f / (float)(Nn * KK);
  float S1 = stats[(b * OO + o) * 2 + 0];
  float S2 = stats[(b * OO + o) * 2 + 1];
  float mean = S1 * inv_cnt;
  float var  = S2 * inv_cnt - mean * mean;
  float istd = rsqrtf(var + EPSF);
  for (int i = 0; i < 16; ++i) {
    int n = blockIdx.x * 64 + ys * 16 + i;
    float val = (pm[(size_t)(b * Nn + n) * OO + o] - mean) * istd;
    val = (val >= 0.f) ? val : SLOPEF * val;
    tile[ys * 16 + i][o] = val;
  }
  __syncthreads();
  int nb = blockIdx.x * 64;
  for (int i = 0; i < 16; ++i) {
    int oo = ys * 16 + i;
    out[(size_t)(b * OO + oo) * Nn + nb + o] = tile[o][oo];
  }
}

// ---------------- launch ---------------------------------------------------------------------

extern "C" void kernel_launch(void* const* d_in, const int* in_sizes, int n_in,
                              void* d_out, int out_size, void* d_ws, size_t ws_size,
                              hipStream_t stream) {
  const float* x = (const float*)d_in[0];
  const float* W = (const float*)d_in[1];
  float* out = (float*)d_out;

  char* ws = (char*)d_ws;
  int*    idx   = (int*)ws;                                     // 2,621,440 B
  float*  u     = (float*)(ws + 2621440);                       // 8,388,608 B (becomes pm)
  float*  v     = (float*)(ws + 2621440 + 8388608);             // 8,388,608 B
  float*  stats = (float*)(ws + 2621440 + 2 * 8388608);         // 2,048 B
  float4* P     = (float4*)(ws + 2621440 + 2 * 8388608 + 4096); // 524,288 B

  hipMemsetAsync(stats, 0, Bb * OO * 2 * sizeof(float), stream);
  pack_kernel  <<<dim3((Bb * Nn) / 256), 256, 0, stream>>>(x, P);
  knn_kernel   <<<dim3(128, Bb), 512, 0, stream>>>(P, idx);
  uv_kernel    <<<dim3((Bb * Nn * OO) / 256), 256, 0, stream>>>(x, W, u, v);
  gather_kernel<<<dim3(128, Bb), 256, 0, stream>>>(idx, u, v, stats);
  out_kernel   <<<dim3(128, Bb), 256, 0, stream>>>(u, stats, out);
}

// Round 4
// 235.257 us; speedup vs baseline: 2.2003x; 2.2003x over previous
//
#include <hip/hip_runtime.h>

#define Nn 8192
#define Bb 4
#define KK 20
#define OO 64
#define EPSF 1e-5f
#define SLOPEF 0.2f

#define NBUCK 56
#define HSTRIDE 57            // pad: 57 coprime with 32 banks -> conflict-free per-row access
#define CAP 128
#define BOFF 476              // (bits(2^-8) >> 21) = 476
#define CLO 0.00390625f       // 2^-8
#define CHI 63.9999961853f    // 0x427FFFFF, largest float < 64 -> bucket <= 55

// ---------------- pack: P[b][j] = (x,y,z, |x|^2) ------------------------------------------

__global__ __launch_bounds__(256) void pack_kernel(const float* __restrict__ x,
                                                   float4* __restrict__ P) {
  int gid = blockIdx.x * 256 + threadIdx.x;      // b*N + j
  int b = gid >> 13, j = gid & (Nn - 1);
  const float* xb = x + b * 3 * Nn;
  float a0 = xb[j], a1 = xb[Nn + j], a2 = xb[2 * Nn + j];
  P[gid] = make_float4(a0, a1, a2, a0 * a0 + a1 * a1 + a2 * a2);
}

// ---------------- KNN via exact histogram-select (top-20 incl. self) ------------------------
// Phase 1: per-row 56-bucket histogram of distances (branch-free, LDS atomics).
// Phase 2: collect candidates below the critical-bucket upper edge (sortable u64 keys).
// Phase 3: wave 0 selects 20 smallest keys per row; (d,idx)-lex ties == jax top_k stability.

__global__ __launch_bounds__(512, 4) void knn_kernel(const float4* __restrict__ P,
                                                     int* __restrict__ idx_out) {
  __shared__ unsigned long long cdk[64 * CAP];   // 65536 B candidate keys
  __shared__ unsigned hist[64 * HSTRIDE];        // 14592 B
  __shared__ unsigned ccnt[64];                  //   256 B

  const int lane = threadIdx.x & 63;
  const int wid  = __builtin_amdgcn_readfirstlane(threadIdx.x >> 6);
  const int b    = blockIdx.y;
  const int n    = blockIdx.x * 64 + lane;

  for (int t = threadIdx.x; t < 64 * HSTRIDE; t += 512) hist[t] = 0u;
  if (threadIdx.x < 64) ccnt[threadIdx.x] = 0u;

  const float4* __restrict__ Pb  = P + b * Nn;
  const float4* __restrict__ seg = Pb + wid * 1024;   // wave-uniform base -> scalar loads
  const float4 me = Pb[n];

  unsigned* hrow = &hist[lane * HSTRIDE];

  __syncthreads();

  // ---- phase 1: bucketed counting (no branches) ----
  for (int j = 0; j < 1024; j += 4) {
    #pragma unroll
    for (int t = 0; t < 4; ++t) {
      float4 p = seg[j + t];
      float inner = fmaf(p.x, me.x, fmaf(p.y, me.y, p.z * me.z));
      float d  = fmaf(-2.0f, inner, me.w + p.w);
      float dc = fminf(fmaxf(d, CLO), CHI);
      unsigned bk = (__float_as_uint(dc) >> 21) - BOFF;
      atomicAdd(&hrow[bk], 1u);
    }
  }
  __syncthreads();

  // ---- scan: crit = first bucket with cum >= KK (each wave redundantly) ----
  {
    unsigned cum = 0; int crit = 0;
    #pragma unroll 1
    for (int t = 0; t < NBUCK; ++t) {
      cum += hrow[t];
      crit += (cum < KK) ? 1 : 0;
    }
    const float Tup = __uint_as_float((unsigned)(BOFF + crit + 1) << 21);

    // ---- phase 2: collect candidates with clamp(d) < Tup ----
    const int mbase = wid * 1024;
    for (int j = 0; j < 1024; j += 4) {
      float d[4]; bool a[4];
      #pragma unroll
      for (int t = 0; t < 4; ++t) {
        float4 p = seg[j + t];
        float inner = fmaf(p.x, me.x, fmaf(p.y, me.y, p.z * me.z));
        d[t] = fmaf(-2.0f, inner, me.w + p.w);
        float dc = fminf(fmaxf(d[t], CLO), CHI);
        a[t] = dc < Tup;
      }
      if (__any(a[0] | a[1] | a[2] | a[3])) {
        #pragma unroll
        for (int t = 0; t < 4; ++t) {
          if (a[t]) {
            int bb = (int)__float_as_uint(d[t]);
            unsigned s = (unsigned)(bb ^ ((bb >> 31) | 0x80000000));   // float -> sortable uint
            unsigned c = atomicAdd(&ccnt[lane], 1u);
            if (c < CAP)
              cdk[lane * CAP + c] =
                  ((unsigned long long)s << 32) | (unsigned)(mbase + j + t);
          }
        }
      }
    }
  }
  __syncthreads();

  // ---- phase 3: wave 0 selects 20 smallest keys per row ----
  if (wid != 0) return;
  unsigned cnt = ccnt[lane];
  unsigned long long q[KK];
  #pragma unroll
  for (int k = 0; k < KK; ++k) q[k] = ~0ULL;
  int C = (int)(cnt < CAP ? cnt : CAP);
  #pragma unroll 1
  for (int c = 0; c < C; ++c) {
    unsigned long long key = cdk[lane * CAP + c];
    if (key < q[KK - 1]) {
      #pragma unroll
      for (int k = 0; k < KK; ++k) {
        bool sw = key < q[k];
        unsigned long long tq = q[k];
        q[k] = sw ? key : tq;
        key  = sw ? tq : key;
      }
    }
  }
  // exec-masked exact fallback if a row overflowed CAP (practically never; keeps kernel exact)
  if (__any(cnt > CAP)) {
    if (cnt > CAP) {
      #pragma unroll
      for (int k = 0; k < KK; ++k) q[k] = ~0ULL;
      #pragma unroll 1
      for (int j = 0; j < Nn; ++j) {
        float4 p = Pb[j];
        float inner = fmaf(p.x, me.x, fmaf(p.y, me.y, p.z * me.z));
        float dd = fmaf(-2.0f, inner, me.w + p.w);
        int bb = (int)__float_as_uint(dd);
        unsigned s = (unsigned)(bb ^ ((bb >> 31) | 0x80000000));
        unsigned long long key = ((unsigned long long)s << 32) | (unsigned)j;
        if (key < q[KK - 1]) {
          #pragma unroll
          for (int k = 0; k < KK; ++k) {
            bool sw = key < q[k];
            unsigned long long tq = q[k];
            q[k] = sw ? key : tq;
            key  = sw ? tq : key;
          }
        }
      }
    }
  }
  int* op = idx_out + (b * Nn + n) * KK;
  #pragma unroll
  for (int k = 0; k < KK; ++k) op[k] = (int)(q[k] & 0xFFFFFFFFu);
}

// ---------------- u = (Wa-Wb)·x_n, v = Wb·x_n  (layout [b][n][o], o contiguous) -------------

__global__ __launch_bounds__(256) void uv_kernel(const float* __restrict__ x,
                                                 const float* __restrict__ W,
                                                 float* __restrict__ u,
                                                 float* __restrict__ v) {
  int gid = blockIdx.x * 256 + threadIdx.x;
  int o  = gid & 63;
  int bn = gid >> 6;
  int b  = bn >> 13;
  int n  = bn & (Nn - 1);
  const float* xb = x + b * 3 * Nn;
  float x0 = xb[n], x1 = xb[Nn + n], x2 = xb[2 * Nn + n];
  float wa0 = W[o * 6 + 0], wa1 = W[o * 6 + 1], wa2 = W[o * 6 + 2];
  float wb0 = W[o * 6 + 3], wb1 = W[o * 6 + 4], wb2 = W[o * 6 + 5];
  u[gid] = (wa0 - wb0) * x0 + (wa1 - wb1) * x1 + (wa2 - wb2) * x2;
  v[gid] = wb0 * x0 + wb1 * x1 + wb2 * x2;
}

// ---------------- gather v over neighbors: pm = u + max_k v ; accumulate S1,S2 --------------

__global__ __launch_bounds__(256) void gather_kernel(const int* __restrict__ idx,
                                                     float* __restrict__ u,      // in-place -> pm
                                                     const float* __restrict__ v,
                                                     float* __restrict__ stats) {
  __shared__ float ls1[4][64], ls2[4][64];
  int b  = blockIdx.y;
  int o  = threadIdx.x & 63;
  int ys = threadIdx.x >> 6;
  const float* vb = v + (size_t)b * Nn * OO;
  float s1 = 0.f, s2 = 0.f;
  for (int i = 0; i < 16; ++i) {
    int n = blockIdx.x * 64 + ys * 16 + i;
    const int* ip = idx + (b * Nn + n) * KK;
    float un = u[(size_t)(b * Nn + n) * OO + o];
    float sv = 0.f, sv2 = 0.f, mv = -__builtin_inff();
    #pragma unroll
    for (int k = 0; k < KK; ++k) {
      int j = ip[k];
      float val = vb[(size_t)j * OO + o];
      sv += val; sv2 += val * val; mv = fmaxf(mv, val);
    }
    u[(size_t)(b * Nn + n) * OO + o] = un + mv;
    s1 += (float)KK * un + sv;
    s2 += (float)KK * un * un + 2.f * un * sv + sv2;
  }
  ls1[ys][o] = s1; ls2[ys][o] = s2;
  __syncthreads();
  if (ys == 0) {
    float t1 = ls1[0][o] + ls1[1][o] + ls1[2][o] + ls1[3][o];
    float t2 = ls2[0][o] + ls2[1][o] + ls2[2][o] + ls2[3][o];
    atomicAdd(&stats[(b * OO + o) * 2 + 0], t1);
    atomicAdd(&stats[(b * OO + o) * 2 + 1], t2);
  }
}

// ---------------- finalize: normalize + lrelu + transpose to [b][o][n] ----------------------

__global__ __launch_bounds__(256) void out_kernel(const float* __restrict__ pm,
                                                  const float* __restrict__ stats,
                                                  float* __restrict__ out) {
  __shared__ float tile[64][65];
  int b  = blockIdx.y;
  int o  = threadIdx.x & 63;
  int ys = threadIdx.x >> 6;
  const float inv_cnt = 1.0f / (float)(Nn * KK);
  float S1 = stats[(b * OO + o) * 2 + 0];
  float S2 = stats[(b * OO + o) * 2 + 1];
  float mean = S1 * inv_cnt;
  float var  = S2 * inv_cnt - mean * mean;
  float istd = rsqrtf(var + EPSF);
  for (int i = 0; i < 16; ++i) {
    int n = blockIdx.x * 64 + ys * 16 + i;
    float val = (pm[(size_t)(b * Nn + n) * OO + o] - mean) * istd;
    val = (val >= 0.f) ? val : SLOPEF * val;
    tile[ys * 16 + i][o] = val;
  }
  __syncthreads();
  int nb = blockIdx.x * 64;
  for (int i = 0; i < 16; ++i) {
    int oo = ys * 16 + i;
    out[(size_t)(b * OO + oo) * Nn + nb + o] = tile[o][oo];
  }
}

// ---------------- launch ---------------------------------------------------------------------

extern "C" void kernel_launch(void* const* d_in, const int* in_sizes, int n_in,
                              void* d_out, int out_size, void* d_ws, size_t ws_size,
                              hipStream_t stream) {
  const float* x = (const float*)d_in[0];
  const float* W = (const float*)d_in[1];
  float* out = (float*)d_out;

  char* ws = (char*)d_ws;
  int*    idx   = (int*)ws;                                     // 2,621,440 B
  float*  u     = (float*)(ws + 2621440);                       // 8,388,608 B (becomes pm)
  float*  v     = (float*)(ws + 2621440 + 8388608);             // 8,388,608 B
  float*  stats = (float*)(ws + 2621440 + 2 * 8388608);         // 2,048 B
  float4* P     = (float4*)(ws + 2621440 + 2 * 8388608 + 4096); // 524,288 B

  hipMemsetAsync(stats, 0, Bb * OO * 2 * sizeof(float), stream);
  pack_kernel  <<<dim3((Bb * Nn) / 256), 256, 0, stream>>>(x, P);
  knn_kernel   <<<dim3(128, Bb), 512, 0, stream>>>(P, idx);
  uv_kernel    <<<dim3((Bb * Nn * OO) / 256), 256, 0, stream>>>(x, W, u, v);
  gather_kernel<<<dim3(128, Bb), 256, 0, stream>>>(idx, u, v, stats);
  out_kernel   <<<dim3(128, Bb), 256, 0, stream>>>(u, stats, out);
}

// Round 5
// 187.250 us; speedup vs baseline: 2.7644x; 1.2564x over previous
//
#include <hip/hip_runtime.h>

#define Nn 8192
#define Bb 4
#define KK 20
#define OO 64
#define EPSF 1e-5f
#define SLOPEF 0.2f

#define NBUCK 56
#define CAP 64                // E[C]~26; exact fallback covers overflow
#define BOFF 476              // (bits(2^-8) >> 21)
#define CLO 0.00390625f       // 2^-8
#define CHI 63.9999961853f    // 0x427FFFFF, largest float < 64 -> bucket <= 55
#define SEG 512               // points per wave (16 waves x 512 = 8192)

// ---------------- pack: P[b][j] = (x,y,z, |x|^2) ------------------------------------------

__global__ __launch_bounds__(256) void pack_kernel(const float* __restrict__ x,
                                                   float4* __restrict__ P) {
  int gid = blockIdx.x * 256 + threadIdx.x;      // b*N + j
  int b = gid >> 13, j = gid & (Nn - 1);
  const float* xb = x + b * 3 * Nn;
  float a0 = xb[j], a1 = xb[Nn + j], a2 = xb[2 * Nn + j];
  P[gid] = make_float4(a0, a1, a2, a0 * a0 + a1 * a1 + a2 * a2);
}

// ---------------- KNN via exact histogram-select (top-20 incl. self) ------------------------
// 1024 threads = 16 waves; wave w scans pts [w*512, w*512+512) for the same 64 rows
// (lane = row). LDS layouts transposed: [bk][lane] / [c][lane] -> bank = lane -> conflict-free.
// Output k-order is free (downstream max/sum over k); set exactness via distinct u64 keys.

__global__ __launch_bounds__(1024, 8) void knn_kernel(const float4* __restrict__ P,
                                                      int* __restrict__ idx_out) {
  __shared__ unsigned long long cdk[CAP * 64];   // [c][lane]  32768 B
  __shared__ unsigned hist[NBUCK * 64];          // [bk][lane] 14336 B
  __shared__ unsigned ccnt[64];

  const int lane = threadIdx.x & 63;
  const int wid  = __builtin_amdgcn_readfirstlane(threadIdx.x >> 6);
  const int b    = blockIdx.y;
  const int n    = blockIdx.x * 64 + lane;

  for (int t = threadIdx.x; t < NBUCK * 64; t += 1024) hist[t] = 0u;
  if (threadIdx.x < 64) ccnt[threadIdx.x] = 0u;

  const float4* __restrict__ Pb  = P + b * Nn;
  const float4* __restrict__ seg = Pb + wid * SEG;   // wave-uniform base -> scalar loads
  const float4 me = Pb[n];

  // bucket address = ((bits>>21) << 8) + rowoff   (bytes), rowoff folds -BOFF and lane
  unsigned* hrow0 = &hist[lane] - (BOFF << 6);

  __syncthreads();

  // ---- phase 1: bucketed counting (branch-free) ----
  for (int j = 0; j < SEG; j += 4) {
    #pragma unroll
    for (int t = 0; t < 4; ++t) {
      float4 p = seg[j + t];
      float inner = fmaf(p.x, me.x, fmaf(p.y, me.y, p.z * me.z));
      float d  = fmaf(-2.0f, inner, me.w + p.w);
      float dc = __builtin_amdgcn_fmed3f(d, CLO, CHI);
      atomicAdd(hrow0 + ((__float_as_uint(dc) >> 21) << 6), 1u);
    }
  }
  __syncthreads();

  // ---- scan: crit = first bucket with cum >= KK (each wave redundantly, 56 iters) ----
  unsigned cum = 0; int crit = 0;
  #pragma unroll 1
  for (int t = 0; t < NBUCK; ++t) {
    cum += hist[t * 64 + lane];
    crit += (cum < KK) ? 1 : 0;
  }
  const float Tup = __uint_as_float((unsigned)(BOFF + crit + 1) << 21);

  // ---- phase 2: collect candidates with clamp(d) < Tup ----
  const int mbase = wid * SEG;
  for (int j = 0; j < SEG; j += 4) {
    float d[4]; bool a[4];
    #pragma unroll
    for (int t = 0; t < 4; ++t) {
      float4 p = seg[j + t];
      float inner = fmaf(p.x, me.x, fmaf(p.y, me.y, p.z * me.z));
      d[t] = fmaf(-2.0f, inner, me.w + p.w);
      float dc = __builtin_amdgcn_fmed3f(d[t], CLO, CHI);
      a[t] = dc < Tup;
    }
    if (__any(a[0] | a[1] | a[2] | a[3])) {
      #pragma unroll
      for (int t = 0; t < 4; ++t) {
        if (a[t]) {
          int bb = (int)__float_as_uint(d[t]);
          unsigned s = (unsigned)(bb ^ ((bb >> 31) | 0x80000000));   // float -> sortable uint
          unsigned c = atomicAdd(&ccnt[lane], 1u);
          if (c < CAP)
            cdk[c * 64 + lane] = ((unsigned long long)s << 32) | (unsigned)(mbase + j + t);
        }
      }
    }
  }
  __syncthreads();

  // ---- phase 3: wave 0 selects the 20 smallest keys per row (set semantics) ----
  if (wid != 0) return;
  unsigned cnt = ccnt[lane];
  unsigned long long q[KK];
  #pragma unroll
  for (int k = 0; k < KK; ++k) q[k] = ~0ULL;
  int C = (int)(cnt < CAP ? cnt : CAP);
  #pragma unroll 1
  for (int c = 0; c < C; ++c) {
    unsigned long long key = cdk[c * 64 + lane];
    if (key < q[KK - 1]) {
      #pragma unroll
      for (int k = 0; k < KK; ++k) {
        bool sw = key < q[k];
        unsigned long long tq = q[k];
        q[k] = sw ? key : tq;
        key  = sw ? tq : key;
      }
    }
  }
  // exec-masked exact fallback if a row overflowed CAP (deterministically absent for this
  // input in practice; keeps the kernel unconditionally exact)
  if (__any(cnt > CAP)) {
    if (cnt > CAP) {
      #pragma unroll
      for (int k = 0; k < KK; ++k) q[k] = ~0ULL;
      #pragma unroll 1
      for (int j = 0; j < Nn; ++j) {
        float4 p = Pb[j];
        float inner = fmaf(p.x, me.x, fmaf(p.y, me.y, p.z * me.z));
        float dd = fmaf(-2.0f, inner, me.w + p.w);
        int bb = (int)__float_as_uint(dd);
        unsigned s = (unsigned)(bb ^ ((bb >> 31) | 0x80000000));
        unsigned long long key = ((unsigned long long)s << 32) | (unsigned)j;
        if (key < q[KK - 1]) {
          #pragma unroll
          for (int k = 0; k < KK; ++k) {
            bool sw = key < q[k];
            unsigned long long tq = q[k];
            q[k] = sw ? key : tq;
            key  = sw ? tq : key;
          }
        }
      }
    }
  }
  int* op = idx_out + (b * Nn + n) * KK;
  #pragma unroll
  for (int k = 0; k < KK; ++k) op[k] = (int)(q[k] & 0xFFFFFFFFu);
}

// ---------------- u = (Wa-Wb)·x_n, v = Wb·x_n  (layout [b][n][o], o contiguous) -------------

__global__ __launch_bounds__(256) void uv_kernel(const float* __restrict__ x,
                                                 const float* __restrict__ W,
                                                 float* __restrict__ u,
                                                 float* __restrict__ v) {
  int gid = blockIdx.x * 256 + threadIdx.x;
  int o  = gid & 63;
  int bn = gid >> 6;
  int b  = bn >> 13;
  int n  = bn & (Nn - 1);
  const float* xb = x + b * 3 * Nn;
  float x0 = xb[n], x1 = xb[Nn + n], x2 = xb[2 * Nn + n];
  float wa0 = W[o * 6 + 0], wa1 = W[o * 6 + 1], wa2 = W[o * 6 + 2];
  float wb0 = W[o * 6 + 3], wb1 = W[o * 6 + 4], wb2 = W[o * 6 + 5];
  u[gid] = (wa0 - wb0) * x0 + (wa1 - wb1) * x1 + (wa2 - wb2) * x2;
  v[gid] = wb0 * x0 + wb1 * x1 + wb2 * x2;
}

// ---------------- gather v over neighbors: pm = u + max_k v ; accumulate S1,S2 --------------

__global__ __launch_bounds__(256) void gather_kernel(const int* __restrict__ idx,
                                                     float* __restrict__ u,      // in-place -> pm
                                                     const float* __restrict__ v,
                                                     float* __restrict__ stats) {
  __shared__ float ls1[4][64], ls2[4][64];
  int b  = blockIdx.y;
  int o  = threadIdx.x & 63;
  int ys = threadIdx.x >> 6;
  const float* vb = v + (size_t)b * Nn * OO;
  float s1 = 0.f, s2 = 0.f;
  for (int i = 0; i < 16; ++i) {
    int n = blockIdx.x * 64 + ys * 16 + i;
    const int* ip = idx + (b * Nn + n) * KK;
    float un = u[(size_t)(b * Nn + n) * OO + o];
    float sv = 0.f, sv2 = 0.f, mv = -__builtin_inff();
    #pragma unroll
    for (int k = 0; k < KK; ++k) {
      int j = ip[k];
      float val = vb[(size_t)j * OO + o];
      sv += val; sv2 += val * val; mv = fmaxf(mv, val);
    }
    u[(size_t)(b * Nn + n) * OO + o] = un + mv;
    s1 += (float)KK * un + sv;
    s2 += (float)KK * un * un + 2.f * un * sv + sv2;
  }
  ls1[ys][o] = s1; ls2[ys][o] = s2;
  __syncthreads();
  if (ys == 0) {
    float t1 = ls1[0][o] + ls1[1][o] + ls1[2][o] + ls1[3][o];
    float t2 = ls2[0][o] + ls2[1][o] + ls2[2][o] + ls2[3][o];
    atomicAdd(&stats[(b * OO + o) * 2 + 0], t1);
    atomicAdd(&stats[(b * OO + o) * 2 + 1], t2);
  }
}

// ---------------- finalize: normalize + lrelu + transpose to [b][o][n] ----------------------

__global__ __launch_bounds__(256) void out_kernel(const float* __restrict__ pm,
                                                  const float* __restrict__ stats,
                                                  float* __restrict__ out) {
  __shared__ float tile[64][65];
  int b  = blockIdx.y;
  int o  = threadIdx.x & 63;
  int ys = threadIdx.x >> 6;
  const float inv_cnt = 1.0f / (float)(Nn * KK);
  float S1 = stats[(b * OO + o) * 2 + 0];
  float S2 = stats[(b * OO + o) * 2 + 1];
  float mean = S1 * inv_cnt;
  float var  = S2 * inv_cnt - mean * mean;
  float istd = rsqrtf(var + EPSF);
  for (int i = 0; i < 16; ++i) {
    int n = blockIdx.x * 64 + ys * 16 + i;
    float val = (pm[(size_t)(b * Nn + n) * OO + o] - mean) * istd;
    val = (val >= 0.f) ? val : SLOPEF * val;
    tile[ys * 16 + i][o] = val;
  }
  __syncthreads();
  int nb = blockIdx.x * 64;
  for (int i = 0; i < 16; ++i) {
    int oo = ys * 16 + i;
    out[(size_t)(b * OO + oo) * Nn + nb + o] = tile[o][oo];
  }
}

// ---------------- launch ---------------------------------------------------------------------

extern "C" void kernel_launch(void* const* d_in, const int* in_sizes, int n_in,
                              void* d_out, int out_size, void* d_ws, size_t ws_size,
                              hipStream_t stream) {
  const float* x = (const float*)d_in[0];
  const float* W = (const float*)d_in[1];
  float* out = (float*)d_out;

  char* ws = (char*)d_ws;
  int*    idx   = (int*)ws;                                     // 2,621,440 B
  float*  u     = (float*)(ws + 2621440);                       // 8,388,608 B (becomes pm)
  float*  v     = (float*)(ws + 2621440 + 8388608);             // 8,388,608 B
  float*  stats = (float*)(ws + 2621440 + 2 * 8388608);         // 2,048 B
  float4* P     = (float4*)(ws + 2621440 + 2 * 8388608 + 4096); // 524,288 B

  hipMemsetAsync(stats, 0, Bb * OO * 2 * sizeof(float), stream);
  pack_kernel  <<<dim3((Bb * Nn) / 256), 256, 0, stream>>>(x, P);
  knn_kernel   <<<dim3(128, Bb), 1024, 0, stream>>>(P, idx);
  uv_kernel    <<<dim3((Bb * Nn * OO) / 256), 256, 0, stream>>>(x, W, u, v);
  gather_kernel<<<dim3(128, Bb), 256, 0, stream>>>(idx, u, v, stats);
  out_kernel   <<<dim3(128, Bb), 256, 0, stream>>>(u, stats, out);
}